// Round 3
// baseline (944.679 us; speedup 1.0000x reference)
//
#include <hip/hip_runtime.h>
#include <math.h>

// ---------------------------------------------------------------------------
// Encoder block on MI355X (gfx950).  B=4, T=2048, E=1024, H=16, Dh=64, FF=4096.
// Inputs may be bf16 or fp32 (harness-dependent): a detector kernel classifies
// x's buffer, then converts decide; all compute kernels run on internal bf16.
// ---------------------------------------------------------------------------

using u16 = unsigned short;
typedef __bf16 bf16x8 __attribute__((ext_vector_type(8)));
typedef unsigned short u16x8 __attribute__((ext_vector_type(8)));
typedef unsigned short u16x4 __attribute__((ext_vector_type(4)));
typedef float f32x4 __attribute__((ext_vector_type(4)));

__device__ __forceinline__ float bf2f(u16 h) {
  return __uint_as_float(((unsigned int)h) << 16);
}
__device__ __forceinline__ u16 f2bf(float f) {  // RNE
  unsigned int u = __float_as_uint(f);
  u += 0x7fffu + ((u >> 16) & 1u);
  return (u16)(u >> 16);
}

__device__ __forceinline__ void gload_lds16(const void* g, void* l) {
  __builtin_amdgcn_global_load_lds(
      (__attribute__((address_space(1))) void*)(g),
      (__attribute__((address_space(3))) void*)(l), 16, 0, 0);
}

// ---------------------------------------------------------------------------
// Dtype detector: interpret first 2048 u16 of x as bf16; true-bf16 data is
// ~100% in [1e-4, 64]; fp32 data read as u16 pairs is ~54%.  flag=1 -> fp32.
// ---------------------------------------------------------------------------
__global__ __launch_bounds__(256) void detect_dtype(const u16* __restrict__ x,
                                                    int* __restrict__ flag) {
  __shared__ int cnt[256];
  int c = 0;
#pragma unroll
  for (int j = 0; j < 8; ++j) {
    float v = bf2f(x[threadIdx.x * 8 + j]);
    float a = fabsf(v);
    if (a >= 1e-4f && a <= 64.0f) ++c;  // NaN fails both -> not counted
  }
  cnt[threadIdx.x] = c;
  __syncthreads();
  if (threadIdx.x == 0) {
    int t = 0;
    for (int i = 0; i < 256; ++i) t += cnt[i];
    flag[0] = (t < 1638) ? 1 : 0;  // <80% in-range => fp32
  }
}

// ---------------------------------------------------------------------------
// Elementwise convert raw input -> bf16 (flag: 1=fp32 source, 0=bf16 copy).
// ---------------------------------------------------------------------------
__global__ __launch_bounds__(256) void cvt_copy(const void* __restrict__ in,
                                                u16* __restrict__ out,
                                                const int* __restrict__ flagp,
                                                long n) {
  long idx = ((long)blockIdx.x * 256 + threadIdx.x) * 4;
  if (idx >= n) return;
  if (*flagp) {
    float4 v = *(const float4*)((const float*)in + idx);
    out[idx] = f2bf(v.x); out[idx + 1] = f2bf(v.y);
    out[idx + 2] = f2bf(v.z); out[idx + 3] = f2bf(v.w);
  } else {
    *(u16x4*)(out + idx) = *(const u16x4*)((const u16*)in + idx);
  }
}

// 7 small vectors -> packed bf16 vec area. block = one vector.
__global__ __launch_bounds__(256) void cvt_vecs(
    const void* s0, const void* s1, const void* s2, const void* s3,
    const void* s4, const void* s5, const void* s6, u16* __restrict__ dst,
    const int* __restrict__ flagp) {
  const int lens[7] = {1024, 1024, 1024, 4096, 1024, 1024, 1024};
  const int offs[7] = {0, 1024, 2048, 3072, 7168, 8192, 9216};
  const void* srcs[7] = {s0, s1, s2, s3, s4, s5, s6};
  int w = blockIdx.x;
  int f = *flagp;
  for (int i = threadIdx.x; i < lens[w]; i += 256)
    dst[offs[w] + i] = f ? f2bf(((const float*)srcs[w])[i])
                         : ((const u16*)srcs[w])[i];
}

// ---------------------------------------------------------------------------
// Batched transpose + convert: out[b][c*R+r] = cvt(in[b][r*C+c]). R,C % 32 == 0.
// ---------------------------------------------------------------------------
__global__ __launch_bounds__(256) void transpose_cvt(
    const void* __restrict__ in, u16* __restrict__ out, int R, int C,
    long inBS, long outBS, const int* __restrict__ flagp) {
  __shared__ u16 tile[32][33];
  int f = *flagp;
  u16* ob = out + (long)blockIdx.z * outBS;
  int c = blockIdx.x * 32 + threadIdx.x;
  int r0 = blockIdx.y * 32;
  if (f) {
    const float* ib = (const float*)in + (long)blockIdx.z * inBS;
#pragma unroll
    for (int i = threadIdx.y; i < 32; i += 8)
      tile[i][threadIdx.x] = f2bf(ib[(long)(r0 + i) * C + c]);
  } else {
    const u16* ib = (const u16*)in + (long)blockIdx.z * inBS;
#pragma unroll
    for (int i = threadIdx.y; i < 32; i += 8)
      tile[i][threadIdx.x] = ib[(long)(r0 + i) * C + c];
  }
  __syncthreads();
  int r = r0 + threadIdx.x;
  int c0 = blockIdx.x * 32;
#pragma unroll
  for (int i = threadIdx.y; i < 32; i += 8)
    ob[(long)(c0 + i) * R + r] = tile[threadIdx.x][i];
}

// ---------------------------------------------------------------------------
// GEMM: C[M,N] = A[M,K] @ Bt[N,K]^T (+ epilogue).  M,N % 128 == 0, K % 32 == 0.
// EPI 0: bf16 store.  EPI 1: +bias, f32 store.  EPI 2: +bias, gelu, bf16 store.
// m97 structure: 128x128 tile, BK=32, 4 waves x (4x4) mfma_f32_16x16x32_bf16.
// ---------------------------------------------------------------------------
template <int EPI>
__global__ __launch_bounds__(256) void gemm_bt(
    const u16* __restrict__ A, const u16* __restrict__ Bt,
    const u16* __restrict__ bias, void* __restrict__ Cout,
    int M, int N, int K) {
  __shared__ u16 As[128 * 32];
  __shared__ u16 Bs[128 * 32];
  const int tid = threadIdx.x;
  const int wave = tid >> 6, lane = tid & 63;
  const int m0 = blockIdx.x * 128, n0 = blockIdx.y * 128;
  const int wm = (wave >> 1) * 64, wn = (wave & 1) * 64;
  const int srow = lane >> 2, skoff = (lane & 3) * 8;

  const u16* ag[2];
  const u16* bg[2];
  u16* al[2];
  u16* bl[2];
#pragma unroll
  for (int p = 0; p < 2; ++p) {
    int r = p * 64 + wave * 16;
    ag[p] = A + (long)(m0 + r + srow) * K + skoff;
    bg[p] = Bt + (long)(n0 + r + srow) * K + skoff;
    al[p] = As + r * 32;  // wave-uniform LDS base (HW adds lane*16B)
    bl[p] = Bs + r * 32;
  }

  f32x4 acc[4][4] = {};
  const int lr = lane & 15, lk = (lane >> 4) * 8;

  for (int k0 = 0; k0 < K; k0 += 32) {
#pragma unroll
    for (int p = 0; p < 2; ++p) {
      gload_lds16(ag[p] + k0, al[p]);
      gload_lds16(bg[p] + k0, bl[p]);
    }
    __syncthreads();
    bf16x8 af[4], bfr[4];
#pragma unroll
    for (int t = 0; t < 4; ++t) {
      af[t] = *(const bf16x8*)(As + (wm + t * 16 + lr) * 32 + lk);
      bfr[t] = *(const bf16x8*)(Bs + (wn + t * 16 + lr) * 32 + lk);
    }
#pragma unroll
    for (int mt = 0; mt < 4; ++mt)
#pragma unroll
      for (int nt = 0; nt < 4; ++nt)
        acc[mt][nt] = __builtin_amdgcn_mfma_f32_16x16x32_bf16(
            af[mt], bfr[nt], acc[mt][nt], 0, 0, 0);
    __syncthreads();
  }

  // C/D layout (verified m89/m91): col = lane&15, row = (lane>>4)*4 + reg
  const int rq = (lane >> 4) * 4, cl = lane & 15;
#pragma unroll
  for (int mt = 0; mt < 4; ++mt)
#pragma unroll
    for (int nt = 0; nt < 4; ++nt) {
      int col = n0 + wn + nt * 16 + cl;
#pragma unroll
      for (int r = 0; r < 4; ++r) {
        long row = (long)(m0 + wm + mt * 16 + rq + r);
        float v = acc[mt][nt][r];
        if (EPI == 0) {
          ((u16*)Cout)[row * N + col] = f2bf(v);
        } else if (EPI == 1) {
          v += bf2f(bias[col]);
          ((float*)Cout)[row * N + col] = v;
        } else {
          v += bf2f(bias[col]);
          v = 0.5f * v * (1.0f + erff(v * 0.70710678118654752f));
          ((u16*)Cout)[row * N + col] = f2bf(v);
        }
      }
    }
}

// ---------------------------------------------------------------------------
// Flash attention.  qkv: [B*T, 3072] bf16 (q|k|v each 1024 = 16 heads x 64).
// cat: [B*T, 1024] bf16.  Grid: (T/64, B*H).  Block: 256 (4 waves).
// ---------------------------------------------------------------------------
__global__ __launch_bounds__(256) void flash_attn(
    const u16* __restrict__ qkv, u16* __restrict__ cat) {
  const int T = 2048, LD = 3072;
  const int bh = blockIdx.y;
  const int b = bh >> 4, h = bh & 15;
  const int tid = threadIdx.x, wave = tid >> 6, lane = tid & 63;
  const int lr = lane & 15, lq = lane >> 4;

  __shared__ u16 Vt[64 * 72];  // [d][key], stride 72
  __shared__ u16 Ps[64 * 72];  // [qrow][key]

  const u16* Qb = qkv + (long)(b * 2048) * LD + h * 64;
  const u16* Kb = Qb + 1024;
  const u16* Vb = Qb + 2048;

  const int qrow = blockIdx.x * 64 + wave * 16 + lr;
  bf16x8 aq[2];
#pragma unroll
  for (int kt = 0; kt < 2; ++kt)
    aq[kt] = *(const bf16x8*)(Qb + (long)qrow * LD + kt * 32 + lq * 8);

  f32x4 o[4] = {};
  float m_i[4], l_i[4];
#pragma unroll
  for (int r = 0; r < 4; ++r) { m_i[r] = -1e30f; l_i[r] = 0.0f; }

  const int vkey = tid & 63;        // key row this thread stages
  const int vd0 = (tid >> 6) * 16;  // 16-d slab; 4 waves cover d=0..63

  for (int j0 = 0; j0 < T; j0 += 64) {
    __syncthreads();
    {
      const u16* vsrc = Vb + (long)(j0 + vkey) * LD + vd0;
      u16x8 v0 = *(const u16x8*)(vsrc);
      u16x8 v1 = *(const u16x8*)(vsrc + 8);
#pragma unroll
      for (int j = 0; j < 8; ++j) {
        Vt[(vd0 + j) * 72 + vkey] = v0[j];
        Vt[(vd0 + 8 + j) * 72 + vkey] = v1[j];
      }
    }

    f32x4 s[4] = {};
#pragma unroll
    for (int nt = 0; nt < 4; ++nt)
#pragma unroll
      for (int kt = 0; kt < 2; ++kt) {
        bf16x8 bk = *(const bf16x8*)(Kb + (long)(j0 + nt * 16 + lr) * LD +
                                     kt * 32 + lq * 8);
        s[nt] = __builtin_amdgcn_mfma_f32_16x16x32_bf16(aq[kt], bk, s[nt], 0, 0, 0);
      }
#pragma unroll
    for (int nt = 0; nt < 4; ++nt)
#pragma unroll
      for (int r = 0; r < 4; ++r) s[nt][r] *= 0.125f;

    float rowmax[4];
#pragma unroll
    for (int r = 0; r < 4; ++r)
      rowmax[r] = fmaxf(fmaxf(s[0][r], s[1][r]), fmaxf(s[2][r], s[3][r]));
#pragma unroll
    for (int off = 1; off < 16; off <<= 1)
#pragma unroll
      for (int r = 0; r < 4; ++r)
        rowmax[r] = fmaxf(rowmax[r], __shfl_xor(rowmax[r], off, 64));

    float alpha[4], rsum[4];
#pragma unroll
    for (int r = 0; r < 4; ++r) {
      float mn = fmaxf(m_i[r], rowmax[r]);
      alpha[r] = __expf(m_i[r] - mn);
      m_i[r] = mn;
    }
#pragma unroll
    for (int nt = 0; nt < 4; ++nt)
#pragma unroll
      for (int r = 0; r < 4; ++r) s[nt][r] = __expf(s[nt][r] - m_i[r]);
#pragma unroll
    for (int r = 0; r < 4; ++r)
      rsum[r] = s[0][r] + s[1][r] + s[2][r] + s[3][r];
#pragma unroll
    for (int off = 1; off < 16; off <<= 1)
#pragma unroll
      for (int r = 0; r < 4; ++r) rsum[r] += __shfl_xor(rsum[r], off, 64);
#pragma unroll
    for (int r = 0; r < 4; ++r) l_i[r] = l_i[r] * alpha[r] + rsum[r];
#pragma unroll
    for (int nt = 0; nt < 4; ++nt)
#pragma unroll
      for (int r = 0; r < 4; ++r) o[nt][r] *= alpha[r];

    const int prow = wave * 16 + lq * 4;
#pragma unroll
    for (int nt = 0; nt < 4; ++nt)
#pragma unroll
      for (int r = 0; r < 4; ++r)
        Ps[(prow + r) * 72 + nt * 16 + lr] = f2bf(s[nt][r]);

    __syncthreads();

    const int arow = wave * 16 + lr;
#pragma unroll
    for (int kt = 0; kt < 2; ++kt) {
      bf16x8 ap = *(const bf16x8*)(Ps + arow * 72 + kt * 32 + lq * 8);
#pragma unroll
      for (int nt = 0; nt < 4; ++nt) {
        bf16x8 bv = *(const bf16x8*)(Vt + (nt * 16 + lr) * 72 + kt * 32 + lq * 8);
        o[nt] = __builtin_amdgcn_mfma_f32_16x16x32_bf16(ap, bv, o[nt], 0, 0, 0);
      }
    }
  }

  const int trow = blockIdx.x * 64 + wave * 16 + lq * 4;
  u16* ob = cat + (long)(b * 2048) * 1024 + h * 64;
#pragma unroll
  for (int r = 0; r < 4; ++r) {
    float inv = 1.0f / l_i[r];
#pragma unroll
    for (int nt = 0; nt < 4; ++nt)
      ob[(long)(trow + r) * 1024 + nt * 16 + lr] = f2bf(o[nt][r] * inv);
  }
}

// ---------------------------------------------------------------------------
// out[row0+row] = res[row] + LN(y[row]) * g + b.  final_out: dtype per flag.
// ---------------------------------------------------------------------------
__global__ __launch_bounds__(256) void ln_residual(
    const float* __restrict__ y, const u16* __restrict__ res,
    const u16* __restrict__ g, const u16* __restrict__ bb,
    void* __restrict__ out, const int* __restrict__ flagp, int final_out,
    long row0) {
  const long row = blockIdx.x;
  const int tid = threadIdx.x, wave = tid >> 6, lane = tid & 63;
  float4 v = ((const float4*)(y + row * 1024))[tid];
  float s1 = v.x + v.y + v.z + v.w;
  float s2 = v.x * v.x + v.y * v.y + v.z * v.z + v.w * v.w;
#pragma unroll
  for (int off = 1; off < 64; off <<= 1) {
    s1 += __shfl_xor(s1, off, 64);
    s2 += __shfl_xor(s2, off, 64);
  }
  __shared__ float ws1[4], ws2[4];
  if (lane == 0) { ws1[wave] = s1; ws2[wave] = s2; }
  __syncthreads();
  float t1 = ws1[0] + ws1[1] + ws1[2] + ws1[3];
  float t2 = ws2[0] + ws2[1] + ws2[2] + ws2[3];
  float mu = t1 * (1.0f / 1024.0f);
  float var = t2 * (1.0f / 1024.0f) - mu * mu;
  float rstd = rsqrtf(var + 1e-5f);
  int i = tid * 4;
  float yy[4] = {v.x, v.y, v.z, v.w};
  bool f32out = final_out && (*flagp);
  long orow = row0 + row;
#pragma unroll
  for (int j = 0; j < 4; ++j) {
    float o = bf2f(res[row * 1024 + i + j]) +
              (yy[j] - mu) * rstd * bf2f(g[i + j]) + bf2f(bb[i + j]);
    if (f32out)
      ((float*)out)[orow * 1024 + i + j] = o;
    else
      ((u16*)out)[orow * 1024 + i + j] = f2bf(o);
  }
}

// ---------------------------------------------------------------------------
extern "C" void kernel_launch(void* const* d_in, const int* in_sizes, int n_in,
                              void* d_out, int out_size, void* d_ws,
                              size_t ws_size, hipStream_t stream) {
  const void* x_raw = d_in[0];
  const void* Wq = d_in[1];
  const void* Wk = d_in[2];
  const void* Wv = d_in[3];
  const void* Wo = d_in[4];
  const void* bo = d_in[5];
  const void* ln1g = d_in[6];
  const void* ln1b = d_in[7];
  const void* W1 = d_in[8];
  const void* b1 = d_in[9];
  const void* W2 = d_in[10];
  const void* b2 = d_in[11];
  const void* ln2g = d_in[12];
  const void* ln2b = d_in[13];

  char* ws = (char*)d_ws;
  // Region R0 [0,48MB): qkv bf16 -> mha f32 (32MB) -> h1c bf16(32MB)+ffc f32(16MB)
  u16* qkv = (u16*)(ws + 0);              // [8192,3072]
  float* mha = (float*)(ws + 0);          // [8192,1024]
  u16* h1c = (u16*)(ws + 0);              // [4096,4096] chunk
  float* ffc = (float*)(ws + 33554432);   // [4096,1024] chunk
  u16* cat = (u16*)(ws + 50331648);       // [8192,1024]
  u16* x1 = (u16*)(ws + 67108864);        // [8192,1024]
  u16* xb = (u16*)(ws + 83886080);        // [8192,1024] bf16-normalized x
  u16* wqkvt = (u16*)(ws + 100663296);    // [3072,1024]
  u16* wot = (u16*)(ws + 106954752);      // [1024,1024]
  u16* w1t = (u16*)(ws + 109051904);      // [4096,1024]
  u16* w2t = (u16*)(ws + 117440512);      // [1024,4096]
  u16* vecs = (u16*)(ws + 125829120);     // packed bias/gain vectors (bf16)
  int* flag = (int*)(ws + 125853696);     // dtype flag (1 = fp32 inputs)
  // total 125857800 B (~120 MB)

  const u16* v_bo = vecs + 0;
  const u16* v_l1g = vecs + 1024;
  const u16* v_l1b = vecs + 2048;
  const u16* v_b1 = vecs + 3072;
  const u16* v_b2 = vecs + 7168;
  const u16* v_l2g = vecs + 8192;
  const u16* v_l2b = vecs + 9216;

  detect_dtype<<<1, 256, 0, stream>>>((const u16*)x_raw, flag);
  cvt_copy<<<8192, 256, 0, stream>>>(x_raw, xb, flag, 8388608L);
  cvt_vecs<<<7, 256, 0, stream>>>(bo, ln1g, ln1b, b1, b2, ln2g, ln2b, vecs, flag);

  dim3 tb(32, 8);
  // Wq/Wk/Wv per-head [1024,64] -> [64,1024]; qkv col = {q,k,v}*1024 + h*64 + d
  transpose_cvt<<<dim3(2, 32, 16), tb, 0, stream>>>(Wq, wqkvt, 1024, 64, 65536, 65536, flag);
  transpose_cvt<<<dim3(2, 32, 16), tb, 0, stream>>>(Wk, wqkvt + 1048576, 1024, 64, 65536, 65536, flag);
  transpose_cvt<<<dim3(2, 32, 16), tb, 0, stream>>>(Wv, wqkvt + 2097152, 1024, 64, 65536, 65536, flag);
  transpose_cvt<<<dim3(32, 32, 1), tb, 0, stream>>>(Wo, wot, 1024, 1024, 0, 0, flag);
  transpose_cvt<<<dim3(128, 32, 1), tb, 0, stream>>>(W1, w1t, 1024, 4096, 0, 0, flag);
  transpose_cvt<<<dim3(32, 128, 1), tb, 0, stream>>>(W2, w2t, 4096, 1024, 0, 0, flag);

  // qkv = xb @ Wqkv
  gemm_bt<0><<<dim3(64, 24), 256, 0, stream>>>(xb, wqkvt, nullptr, qkv, 8192, 3072, 1024);
  // cat = attention(qkv)
  flash_attn<<<dim3(32, 64), 256, 0, stream>>>(qkv, cat);
  // mha = cat @ Wo + bo (f32)
  gemm_bt<1><<<dim3(64, 8), 256, 0, stream>>>(cat, wot, v_bo, mha, 8192, 1024, 1024);
  // x1 = xb + LN(mha)
  ln_residual<<<8192, 256, 0, stream>>>(mha, xb, v_l1g, v_l1b, x1, flag, 0, 0);

  // FFN in 2 row-chunks of 4096 (fits dead qkv region)
  for (int c = 0; c < 2; ++c) {
    const u16* x1c = x1 + (long)c * 4096 * 1024;
    gemm_bt<2><<<dim3(32, 32), 256, 0, stream>>>(x1c, w1t, v_b1, h1c, 4096, 4096, 1024);
    gemm_bt<1><<<dim3(32, 8), 256, 0, stream>>>(h1c, w2t, v_b2, ffc, 4096, 1024, 4096);
    ln_residual<<<4096, 256, 0, stream>>>(ffc, x1c, v_l2g, v_l2b, d_out, flag, 1,
                                          (long)c * 4096);
  }
}